// Round 3
// baseline (272.927 us; speedup 1.0000x reference)
//
#include <hip/hip_runtime.h>
#include <math.h>

// Problem constants (fixed by the reference).
constexpr int kN  = 250000;
constexpr int kC  = 32;
constexpr int kFC = 16;
constexpr int kFN = 16;
constexpr int kV  = 64;

// ---------------------------------------------------------------------------
// Strategy: log-space fast path + exact fallback.
//
// Fast path (per sample, per class):
//   T_c = K_c + logf(cat_c) + sum_f( -0.5 * ((x_f - m)*rs)^2 ),  rs = fl(1/s)
// where K_c = logf(cp_c) + sum_f logf(1/(2*pi*s^2)) is precomputed. cat_c is
// the *bit-exact* sequential product of gathered cat_probs (same as ref).
//
// Guarantee: if top-1 T >= -86 (top exact score is a normal fp32, since
// e^-86.01 > 4e-38 > FLT_MIN) and top-2 gap >= 4e-3, then
// |T - log(S_exact)| <= ~1e-3 per class (arg rounding 3e-7*|a|, |a|<=~90;
// 16 fma-sum roundings; 1-ulp logf) implies the exact fp32 argmax equals the
// approx argmax. Otherwise (near-ties, exact ties, underflow of all class
// scores -> ref returns first max) the thread recomputes with the reference's
// exact op sequence (validated absmax=0.0 in round 1), including first-max
// tie-break and denormal/zero behavior.
// ---------------------------------------------------------------------------

// d_ws layout (floats): [0 .. 1023]  interleaved {m, rs} per (c,f)
//                       [1024..1055] K_c
__global__ __launch_bounds__(256) void nbc_prep(
    const float* __restrict__ class_probs,
    const float* __restrict__ means,
    const float* __restrict__ stds,
    float* __restrict__ ws)
{
    const int t = threadIdx.x;
    const float two_pi = 2.0f * (float)M_PI;
    for (int i = t; i < kC * kFN; i += 256) {
        float m = means[i];
        float s = stds[i];
        ws[2 * i]     = m;
        ws[2 * i + 1] = 1.0f / s;
    }
    if (t < kC) {
        float k = logf(class_probs[t]);
        for (int f = 0; f < kFN; ++f) {
            float s = stds[t * kFN + f];
            k += logf(1.0f / (two_pi * (s * s)));
        }
        ws[2 * kC * kFN + t] = k;
    }
}

__global__ __launch_bounds__(256) void nbc_main(
    const int*   __restrict__ X_cat,
    const float* __restrict__ X_num,
    const float* __restrict__ class_probs,
    const float* __restrict__ cat_probs,
    const float* __restrict__ means,
    const float* __restrict__ stds,
    const float* __restrict__ ws,
    int* __restrict__ out)
{
    const int n = blockIdx.x * 256 + threadIdx.x;
    if (n >= kN) return;

    // Vector-load the 16 categorical indices and 16 numeric features.
    int   idx[kFC];
    float x  [kFN];
    {
        const int4* p4 = reinterpret_cast<const int4*>(X_cat + (size_t)n * kFC);
        int4 a0 = p4[0], a1 = p4[1], a2 = p4[2], a3 = p4[3];
        idx[0]=a0.x;  idx[1]=a0.y;  idx[2]=a0.z;  idx[3]=a0.w;
        idx[4]=a1.x;  idx[5]=a1.y;  idx[6]=a1.z;  idx[7]=a1.w;
        idx[8]=a2.x;  idx[9]=a2.y;  idx[10]=a2.z; idx[11]=a2.w;
        idx[12]=a3.x; idx[13]=a3.y; idx[14]=a3.z; idx[15]=a3.w;

        const float4* q4 = reinterpret_cast<const float4*>(X_num + (size_t)n * kFN);
        float4 b0 = q4[0], b1 = q4[1], b2 = q4[2], b3 = q4[3];
        x[0]=b0.x;  x[1]=b0.y;  x[2]=b0.z;  x[3]=b0.w;
        x[4]=b1.x;  x[5]=b1.y;  x[6]=b1.z;  x[7]=b1.w;
        x[8]=b2.x;  x[9]=b2.y;  x[10]=b2.z; x[11]=b2.w;
        x[12]=b3.x; x[13]=b3.y; x[14]=b3.z; x[15]=b3.w;
    }

    const float2* __restrict__ P = reinterpret_cast<const float2*>(ws); // {m,rs}
    const float*  __restrict__ K = ws + 2 * kC * kFN;

    // ---- fast path: log-space argmax with top-2 tracking ----
    float best = -INFINITY, second = -INFINITY;
    int   besti = 0;

    #pragma unroll 2
    for (int c = 0; c < kC; ++c) {
        // Bit-exact categorical product (reference order, ascending f).
        const float* __restrict__ row = cat_probs + (size_t)c * (kFC * kV);
        float cat = row[idx[0]];
        #pragma unroll
        for (int f = 1; f < kFC; ++f) {
            cat *= row[(f << 6) + idx[f]];
        }

        // Gaussian log-term (approx): uniform {m,rs} -> scalar loads via K$.
        float a = 0.0f;
        #pragma unroll
        for (int f = 0; f < kFN; ++f) {
            float2 p = P[c * kFN + f];
            float z = (x[f] - p.x) * p.y;
            a = fmaf(z * z, -0.5f, a);
        }

        float T = (K[c] + logf(cat)) + a;
        if (T > best)        { second = best; best = T; besti = c; }
        else if (T > second) { second = T; }
    }

    if (best >= -86.0f && (best - second) >= 4.0e-3f) {
        out[n] = besti;
        return;
    }

    // ---- exact fallback: reference numerics, bit-identical (round-1 code) ----
    const float two_pi = 2.0f * (float)M_PI;
    float bb = -INFINITY;
    int   bi = 0;
    for (int c = 0; c < kC; ++c) {
        const float* __restrict__ row = cat_probs + (size_t)c * (kFC * kV);
        float cat = row[idx[0]];
        #pragma unroll
        for (int f = 1; f < kFC; ++f) {
            cat *= row[(f << 6) + idx[f]];
        }

        float num;
        #pragma unroll
        for (int f = 0; f < kFN; ++f) {
            float m = means[c * kFN + f];
            float s = stds [c * kFN + f];
            float inv = 1.0f / (two_pi * (s * s));   // same bits as round 1
            float z = (x[f] - m) / s;                // IEEE divide
            float e = expf(-0.5f * (z * z));
            float lik = inv * e;
            num = (f == 0) ? lik : num * lik;
        }

        float pred = (class_probs[c] * cat) * num;   // ((cp*cat)*num) like ref
        if (pred > bb) { bb = pred; bi = c; }        // strict > -> first max
    }
    out[n] = bi;
}

extern "C" void kernel_launch(void* const* d_in, const int* in_sizes, int n_in,
                              void* d_out, int out_size, void* d_ws, size_t ws_size,
                              hipStream_t stream) {
    const int*   X_cat       = (const int*)  d_in[0];
    const float* X_num       = (const float*)d_in[1];
    const float* class_probs = (const float*)d_in[2];
    const float* cat_probs   = (const float*)d_in[3];
    const float* means       = (const float*)d_in[4];
    const float* stds        = (const float*)d_in[5];
    int*   out = (int*)d_out;
    float* ws  = (float*)d_ws;   // 4224 bytes used

    hipLaunchKernelGGL(nbc_prep, dim3(1), dim3(256), 0, stream,
                       class_probs, means, stds, ws);

    dim3 block(256);
    dim3 grid((kN + 255) / 256);
    hipLaunchKernelGGL(nbc_main, grid, block, 0, stream,
                       X_cat, X_num, class_probs, cat_probs, means, stds, ws, out);
}

// Round 4
// 173.974 us; speedup vs baseline: 1.5688x; 1.5688x over previous
//
#include <hip/hip_runtime.h>
#include <math.h>

// Problem constants (fixed by the reference).
constexpr int kN  = 250000;
constexpr int kC  = 32;
constexpr int kFC = 16;
constexpr int kFN = 16;
constexpr int kV  = 64;

// ---------------------------------------------------------------------------
// Log-space fast path + CANDIDATE-ONLY exact fallback.
//
// Fast path (per sample, per class):
//   T_c = K_c + logf(cat_c) + sum_f( -0.5 * ((x_f - m)*rs)^2 ),  rs = fl(1/s)
// cat_c is the bit-exact sequential product of gathered cat_probs (ref order).
// Error bound: |T_c - log(S_exact_c)| <= ~1.2e-3 (arg rounding 3e-7*|a|,
// |a|<=~100; 16 fma roundings; 1-ulp logf). Exact fp32 product path has
// relative error ~2e-6 when the best score is a normal float
// (T_best >= -86  =>  S_best >= e^-86.1 ~ 3.6e-38 > FLT_MIN; partial
// products only shrink since every likelihood factor < 1).
//
// Accept fast result iff T_best >= -86 AND top-2 gap >= 4e-3 (>= 2x bound).
// Otherwise fallback, but exact-score ONLY candidate classes with
// T_c >= T_best - 8e-3 (others provably lose: their true log-score is
// <= T_c + 2e-3 <= best - 6e-3 while true best >= best - 2e-3).
// If T_best < -86 (deep underflow, ~1e-4 of samples) evaluate ALL classes
// with the round-1-validated exact sequence (handles denormals / all-zero
// ties -> first max = ref semantics).
// ---------------------------------------------------------------------------

// d_ws layout (floats): [0 .. 1023]  interleaved {m, rs=1/s} per (c,f)
//                       [1024..1055] K_c
__global__ __launch_bounds__(256) void nbc_prep(
    const float* __restrict__ class_probs,
    const float* __restrict__ means,
    const float* __restrict__ stds,
    float* __restrict__ ws)
{
    const int t = threadIdx.x;
    const float two_pi = 2.0f * (float)M_PI;
    for (int i = t; i < kC * kFN; i += 256) {
        float m = means[i];
        float s = stds[i];
        ws[2 * i]     = m;
        ws[2 * i + 1] = 1.0f / s;
    }
    if (t < kC) {
        float k = logf(class_probs[t]);
        for (int f = 0; f < kFN; ++f) {
            float s = stds[t * kFN + f];
            k += logf(1.0f / (two_pi * (s * s)));
        }
        ws[2 * kC * kFN + t] = k;
    }
}

__global__ __launch_bounds__(256, 4) void nbc_main(
    const int*   __restrict__ X_cat,
    const float* __restrict__ X_num,
    const float* __restrict__ class_probs,
    const float* __restrict__ cat_probs,
    const float* __restrict__ means,
    const float* __restrict__ stds,
    const float* __restrict__ ws,
    int* __restrict__ out)
{
    const int n = blockIdx.x * 256 + threadIdx.x;
    if (n >= kN) return;

    // Vector-load the 16 categorical indices and 16 numeric features.
    int   idx[kFC];
    float x  [kFN];
    {
        const int4* p4 = reinterpret_cast<const int4*>(X_cat + (size_t)n * kFC);
        int4 a0 = p4[0], a1 = p4[1], a2 = p4[2], a3 = p4[3];
        idx[0]=a0.x;  idx[1]=a0.y;  idx[2]=a0.z;  idx[3]=a0.w;
        idx[4]=a1.x;  idx[5]=a1.y;  idx[6]=a1.z;  idx[7]=a1.w;
        idx[8]=a2.x;  idx[9]=a2.y;  idx[10]=a2.z; idx[11]=a2.w;
        idx[12]=a3.x; idx[13]=a3.y; idx[14]=a3.z; idx[15]=a3.w;

        const float4* q4 = reinterpret_cast<const float4*>(X_num + (size_t)n * kFN);
        float4 b0 = q4[0], b1 = q4[1], b2 = q4[2], b3 = q4[3];
        x[0]=b0.x;  x[1]=b0.y;  x[2]=b0.z;  x[3]=b0.w;
        x[4]=b1.x;  x[5]=b1.y;  x[6]=b1.z;  x[7]=b1.w;
        x[8]=b2.x;  x[9]=b2.y;  x[10]=b2.z; x[11]=b2.w;
        x[12]=b3.x; x[13]=b3.y; x[14]=b3.z; x[15]=b3.w;
    }

    const float2* __restrict__ P = reinterpret_cast<const float2*>(ws); // {m,rs}
    const float*  __restrict__ K = ws + 2 * kC * kFN;

    // ---- fast path: log-space argmax with top-2 tracking ----
    float best = -INFINITY, second = -INFINITY;
    int   besti = 0;

    #pragma unroll 4
    for (int c = 0; c < kC; ++c) {
        // Bit-exact categorical product (reference order, ascending f).
        const float* __restrict__ row = cat_probs + (size_t)c * (kFC * kV);
        float cat = row[idx[0]];
        #pragma unroll
        for (int f = 1; f < kFC; ++f) {
            cat *= row[(f << 6) + idx[f]];
        }

        // Gaussian log-term (approx): uniform {m,rs} -> scalar K$ loads.
        float a = 0.0f;
        #pragma unroll
        for (int f = 0; f < kFN; ++f) {
            float2 p = P[c * kFN + f];
            float z = (x[f] - p.x) * p.y;
            a = fmaf(z * z, -0.5f, a);
        }

        float T = (K[c] + logf(cat)) + a;
        if (T > best)        { second = best; best = T; besti = c; }
        else if (T > second) { second = T; }
    }

    if (best >= -86.0f && (best - second) >= 4.0e-3f) {
        out[n] = besti;
        return;
    }

    // ---- fallback: exact scoring of candidate classes only ----
    // thr = -inf in the deep-underflow case -> all classes exact (ref semantics).
    const float thr    = (best >= -86.0f) ? (best - 8.0e-3f) : -INFINITY;
    const float two_pi = 2.0f * (float)M_PI;
    float bb = -INFINITY;
    int   bi = 0;

    #pragma unroll 2
    for (int c = 0; c < kC; ++c) {
        const float* __restrict__ row = cat_probs + (size_t)c * (kFC * kV);
        float cat = row[idx[0]];
        #pragma unroll
        for (int f = 1; f < kFC; ++f) {
            cat *= row[(f << 6) + idx[f]];
        }

        // Recompute T_c (same ops as fast loop; only the <=2e-3 bound matters).
        float a = 0.0f;
        #pragma unroll
        for (int f = 0; f < kFN; ++f) {
            float2 p = P[c * kFN + f];
            float z = (x[f] - p.x) * p.y;
            a = fmaf(z * z, -0.5f, a);
        }
        float T = (K[c] + logf(cat)) + a;

        if (T >= thr) {
            // Exact reference numerics (round-1 validated, bit-identical).
            float num;
            #pragma unroll
            for (int f = 0; f < kFN; ++f) {
                float m = means[c * kFN + f];
                float s = stds [c * kFN + f];
                float inv = 1.0f / (two_pi * (s * s));
                float z = (x[f] - m) / s;              // IEEE divide
                float e = expf(-0.5f * (z * z));
                float lik = inv * e;
                num = (f == 0) ? lik : num * lik;
            }
            float pred = (class_probs[c] * cat) * num; // ((cp*cat)*num) like ref
            if (pred > bb) { bb = pred; bi = c; }      // strict > -> first max
        }
    }
    out[n] = bi;
}

extern "C" void kernel_launch(void* const* d_in, const int* in_sizes, int n_in,
                              void* d_out, int out_size, void* d_ws, size_t ws_size,
                              hipStream_t stream) {
    const int*   X_cat       = (const int*)  d_in[0];
    const float* X_num       = (const float*)d_in[1];
    const float* class_probs = (const float*)d_in[2];
    const float* cat_probs   = (const float*)d_in[3];
    const float* means       = (const float*)d_in[4];
    const float* stds        = (const float*)d_in[5];
    int*   out = (int*)d_out;
    float* ws  = (float*)d_ws;   // 4224 bytes used

    hipLaunchKernelGGL(nbc_prep, dim3(1), dim3(256), 0, stream,
                       class_probs, means, stds, ws);

    dim3 block(256);
    dim3 grid((kN + 255) / 256);
    hipLaunchKernelGGL(nbc_main, grid, block, 0, stream,
                       X_cat, X_num, class_probs, cat_probs, means, stds, ws, out);
}